// Round 15
// baseline (79.445 us; speedup 1.0000x reference)
//
#include <hip/hip_runtime.h>
#include <math.h>

#define BB 8
#define LL 1024
#define HH 8
#define DD 64
#define SS 35
#define UU 35
#define BH (BB*HH)
#define NCHK 4           // attention K/V chunks
#define CHK 256          // keys per chunk
#define RPAD 48          // padded row count (35 -> 48, 3 m-tiles)

#define CSBLOCKS BH      // 64 cumsum blocks (first in grid)
#define MBLOCKS (BB*LL)  // 8192 M blocks

typedef __attribute__((ext_vector_type(8))) short short8;
typedef __attribute__((ext_vector_type(4))) float f32x4;

__device__ __forceinline__ size_t qkv_off(int b, int l, int h, int d) {
    return (((size_t)b*LL + l)*HH + h)*DD + d;
}

__device__ __forceinline__ unsigned short f2bf(float x) {
    unsigned int u = __float_as_uint(x);
    u = (u + 0x7fffu + ((u >> 16) & 1u)) >> 16;
    return (unsigned short)u;
}

__device__ __forceinline__ short8 ld_bf8_g(const float* __restrict__ p) {
    float4 x = *reinterpret_cast<const float4*>(p);
    float4 y = *reinterpret_cast<const float4*>(p + 4);
    short8 r;
    r[0] = (short)f2bf(x.x); r[1] = (short)f2bf(x.y);
    r[2] = (short)f2bf(x.z); r[3] = (short)f2bf(x.w);
    r[4] = (short)f2bf(y.x); r[5] = (short)f2bf(y.y);
    r[6] = (short)f2bf(y.z); r[7] = (short)f2bf(y.w);
    return r;
}

// async global->LDS 16B per lane: dest = ldsbase + lane*16 (wave-uniform base),
// source = per-lane global address.
__device__ __forceinline__ void gload_lds16(const void* g, void* l) {
    __builtin_amdgcn_global_load_lds(
        (const __attribute__((address_space(1))) void*)g,
        (__attribute__((address_space(3))) void*)l, 16, 0, 0);
}

// VALU-only 8-lane-group sum via DPP row_shr:N; lane (lane&7)==7 holds group sum. (Proven R10.)
__device__ __forceinline__ float red8_shr(float p) {
    int t;
    t = __builtin_amdgcn_update_dpp(0, __float_as_int(p), 0x111, 0xF, 0xF, true);
    p += __int_as_float(t);
    t = __builtin_amdgcn_update_dpp(0, __float_as_int(p), 0x112, 0xF, 0xF, true);
    p += __int_as_float(t);
    t = __builtin_amdgcn_update_dpp(0, __float_as_int(p), 0x114, 0xF, 0xF, true);
    p += __int_as_float(t);
    return p;
}

// wave-wide fmax: 4 DPP stages (intra-row) + 2 shfl (cross-row).
__device__ __forceinline__ float wave_fmax64(float x) {
    int t;
    t = __builtin_amdgcn_update_dpp(0, __float_as_int(x), 0xB1, 0xF, 0xF, true);
    x = fmaxf(x, __int_as_float(t));
    t = __builtin_amdgcn_update_dpp(0, __float_as_int(x), 0x4E, 0xF, 0xF, true);
    x = fmaxf(x, __int_as_float(t));
    t = __builtin_amdgcn_update_dpp(0, __float_as_int(x), 0x141, 0xF, 0xF, true);
    x = fmaxf(x, __int_as_float(t));
    t = __builtin_amdgcn_update_dpp(0, __float_as_int(x), 0x140, 0xF, 0xF, true);
    x = fmaxf(x, __int_as_float(t));
    x = fmaxf(x, __shfl_xor(x, 16));
    x = fmaxf(x, __shfl_xor(x, 32));
    return x;
}

__device__ __forceinline__ int wave_imin64(int x) {
    int t;
    t = __builtin_amdgcn_update_dpp(0, x, 0xB1, 0xF, 0xF, true);  x = (t < x) ? t : x;
    t = __builtin_amdgcn_update_dpp(0, x, 0x4E, 0xF, 0xF, true);  x = (t < x) ? t : x;
    t = __builtin_amdgcn_update_dpp(0, x, 0x141, 0xF, 0xF, true); x = (t < x) ? t : x;
    t = __builtin_amdgcn_update_dpp(0, x, 0x140, 0xF, 0xF, true); x = (t < x) ? t : x;
    int y;
    y = __shfl_xor(x, 16); x = (y < x) ? y : x;
    y = __shfl_xor(x, 32); x = (y < x) ? y : x;
    return x;
}

// ---------------- K1: cumsum (blocks 0..63) + M-gather via swizzled global_load_lds ----------------
// M block: 4 waves, one (b,q); wave w owns samples w*9..w*9+8 in 3 DMA batches of 3 rows.
// Row layout XOR-swizzled (p(s)=s^((s>>4)&7), involution): swizzle applied on the DMA
// SOURCE (LDS dest linear per global_load_lds) and on the READ -> bank = j^h, conflict-free.
__global__ __launch_bounds__(256, 6) void kernel_M_cumsum(const float* __restrict__ Q,
                                                          const float* __restrict__ K,
                                                          const float* __restrict__ V,
                                                          const int*   __restrict__ sidx,
                                                          float* __restrict__ M,
                                                          float* __restrict__ out) {
    int blk = blockIdx.x;
    if (blk < CSBLOCKS) {
        // ---- full cumsum for one (b,h): 4 segs x 256 rows, two-pass scan ----
        __shared__ float partial[4][64];
        int bh = blk;
        int b = bh >> 3, h = bh & 7;
        int d = threadIdx.x & 63, seg = threadIdx.x >> 6;
        int l0 = seg * 256;
        const float* vp = V + qkv_off(b, l0, h, d);

        float s = 0.f;
#pragma unroll 8
        for (int i = 0; i < 256; i++) s += vp[(size_t)i * (HH * DD)];
        partial[seg][d] = s;
        __syncthreads();
        float run = 0.f;
#pragma unroll
        for (int ss = 0; ss < 3; ss++) {
            float v = partial[ss][d];
            run += (ss < seg) ? v : 0.f;
        }
        float* op = out + qkv_off(b, l0, h, d);
#pragma unroll 8
        for (int i = 0; i < 256; i++) {
            run += vp[(size_t)i * (HH * DD)];
            op[(size_t)i * (HH * DD)] = run / (float)(l0 + i + 1);
        }
    } else {
        __shared__ float rows[4 * 1536];   // 4 waves x 3 rows x 512 floats = 24KB
        __shared__ float s_mx[4][8];
        __shared__ float s_sm[4][8];
        int mblk = blk - CSBLOCKS;        // CSBLOCKS%8==0 keeps XCD pinning
        int b = mblk & 7;                 // pins this b's K-slice to one XCD's L2
        int q = mblk >> 3;
        int tid = threadIdx.x;
        int w = tid >> 6, lane = tid & 63;
        int h = lane >> 3, j = lane & 7;

        const float* qb = Q + ((size_t)(b * LL + q) * HH + h) * DD + j * 4;
        f32x4 q0 = *reinterpret_cast<const f32x4*>(qb);
        f32x4 q1 = *reinterpret_cast<const f32x4*>(qb + 32);

        const int* sq = sidx + q * SS + w * 9;
        const char* kb = (const char*)(K + (size_t)b * (LL * HH * DD));
        char* region = (char*)(rows + w * 1536);
        const float* region_f = rows + w * 1536;

        // per-lane pre-swizzled source slot offsets (bytes)
        int srcA = (lane ^ ((lane >> 4) & 7)) << 4;          // half A: slots 0..63
        int srcB = 1024 + ((lane ^ (4 | (lane >> 4))) << 4); // half B: slots 64..127
        // read-side physical slots for this lane (logical s1=h*16+j, s2=s1+8)
        int ps1 = ((h << 4) + j) ^ h;
        int ps2 = ((h << 4) + j + 8) ^ h;

        float mx = -INFINITY, sm = 0.f;

#pragma unroll
        for (int batch = 0; batch < 3; batch++) {
            int sl[3];
#pragma unroll
            for (int i = 0; i < 3; i++) {
                int s = batch * 3 + i;
                int ii = (s == 8 && w == 3) ? 7 : s;         // clamp sample 35 -> dup 34
                sl[i] = sq[ii];                              // wave-uniform
            }
#pragma unroll
            for (int r = 0; r < 3; r++) {
                const char* gsrc = kb + (size_t)sl[r] * 2048;
                gload_lds16(gsrc + srcA, region + r * 2048);
                gload_lds16(gsrc + srcB, region + r * 2048 + 1024);
            }
            asm volatile("s_waitcnt vmcnt(0)" ::: "memory");
#pragma unroll
            for (int r = 0; r < 3; r++) {
                const float* rp = region_f + r * 512;
                f32x4 k0 = *reinterpret_cast<const f32x4*>(rp + ps1 * 4);
                f32x4 k1 = *reinterpret_cast<const f32x4*>(rp + ps2 * 4);
                float d = q0.x * k0.x + q0.y * k0.y + q0.z * k0.z + q0.w * k0.w
                        + q1.x * k1.x + q1.y * k1.y + q1.z * k1.z + q1.w * k1.w;
                d = red8_shr(d);
                bool valid = (batch * 3 + r < 8) || (w < 3);
                if (valid) { mx = fmaxf(mx, d); sm += d; }
            }
            asm volatile("s_waitcnt lgkmcnt(0)" ::: "memory");  // reads done before region reuse
        }

        if (j == 7) { s_mx[w][h] = mx; s_sm[w][h] = sm; }
        __syncthreads();
        if (tid < 8) {
            float m2 = -INFINITY, s2 = 0.f;
#pragma unroll
            for (int ww = 0; ww < 4; ww++) {
                m2 = fmaxf(m2, s_mx[ww][tid]);
                s2 += s_sm[ww][tid];
            }
            M[(b * HH + tid) * LL + q] = m2 - s2 * (1.0f / LL);
        }
    }
}

// ---------------- K2: topk, DPP-accelerated single-wave argmax ----------------
__global__ __launch_bounds__(64, 4) void kernel_topk(const float* __restrict__ M,
                                                     int* __restrict__ top) {
    int bh = blockIdx.x, lane = threadIdx.x;
    float v[16];
#pragma unroll
    for (int i = 0; i < 16; i++) v[i] = M[bh * LL + i * 64 + lane];

    for (int k = 0; k < UU; k++) {
        float bv = -INFINITY; int bslot = 0;
#pragma unroll
        for (int i = 0; i < 16; i++) {
            if (v[i] > bv) { bv = v[i]; bslot = i; }      // ascending i -> lowest idx on tie
        }
        float wm = wave_fmax64(bv);
        int gidx = (bv == wm) ? (bslot * 64 + lane) : 0x7fffffff;
        int widx = wave_imin64(gidx);                      // min global index among ties
        if (lane == 0) top[bh * UU + k] = widx;
        if ((widx & 63) == lane) {
            int slot = widx >> 6;
#pragma unroll
            for (int i = 0; i < 16; i++) if (i == slot) v[i] = -INFINITY;
        }
    }
}

// ---------------- K3: MFMA flash-attention partials per (bh, chunk) ----------------
__global__ __launch_bounds__(256) void kernel_attn_part(const float* __restrict__ Q,
                                                        const float* __restrict__ K,
                                                        const float* __restrict__ V,
                                                        const int*   __restrict__ top,
                                                        float* __restrict__ m_ws,
                                                        float* __restrict__ se_ws,
                                                        float* __restrict__ pv_ws) {
    __shared__ unsigned short vt[64 * CHK];      // V^T, 16B-slot swizzled
    __shared__ unsigned short p_lds[RPAD * CHK]; // P (exp'd scores), bf16
    __shared__ float red_m[4][RPAD];
    __shared__ float red_se[4][RPAD];
    __shared__ int   qpos_s[RPAD];

    const int blk = blockIdx.x;          // bh*NCHK + ch
    const int bh  = blk >> 2;
    const int ch  = blk & 3;
    const int b   = bh >> 3, h = bh & 7;
    const int l0  = ch * CHK;
    const int tid = threadIdx.x;
    const int w    = tid >> 6;
    const int lane = tid & 63;
    const int c    = lane & 15;
    const int g    = lane >> 4;
    const float scale = 0.125f;

    if (tid < RPAD) qpos_s[tid] = top[bh * UU + (tid < UU ? tid : UU - 1)];

#pragma unroll
    for (int i = 0; i < 8; i++) {
        int task = i * 256 + tid;
        int d   = task & 63;
        int lq8 = task >> 6;
        float vv[8];
#pragma unroll
        for (int jj = 0; jj < 8; jj++)
            vv[jj] = V[qkv_off(b, l0 + lq8 * 8 + jj, h, d)];
        short8 pk;
#pragma unroll
        for (int jj = 0; jj < 8; jj++) pk[jj] = (short)f2bf(vv[jj]);
        *reinterpret_cast<short8*>(vt + d * CHK + (((lq8 ^ (d & 31)) << 3))) = pk;
    }
    __syncthreads();

    f32x4 acc[3][4];
#pragma unroll
    for (int mt = 0; mt < 3; mt++)
#pragma unroll
        for (int nt = 0; nt < 4; nt++) acc[mt][nt] = (f32x4){0.f, 0.f, 0.f, 0.f};

#pragma unroll
    for (int ks = 0; ks < 2; ks++) {
        int k0 = ks * 32 + g * 8;
        short8 af[3];
#pragma unroll
        for (int mt = 0; mt < 3; mt++) {
            int row = mt * 16 + c;
            af[mt] = ld_bf8_g(Q + qkv_off(b, qpos_s[row], h, k0));
        }
#pragma unroll
        for (int nt = 0; nt < 4; nt++) {
            int kl = l0 + w * 64 + nt * 16 + c;
            short8 bf = ld_bf8_g(K + qkv_off(b, kl, h, k0));
#pragma unroll
            for (int mt = 0; mt < 3; mt++)
                acc[mt][nt] = __builtin_amdgcn_mfma_f32_16x16x32_bf16(af[mt], bf, acc[mt][nt], 0, 0, 0);
        }
    }

    float tmax[3][4];
#pragma unroll
    for (int mt = 0; mt < 3; mt++)
#pragma unroll
        for (int r = 0; r < 4; r++) {
            float m = fmaxf(fmaxf(acc[mt][0][r], acc[mt][1][r]),
                            fmaxf(acc[mt][2][r], acc[mt][3][r]));
            m = fmaxf(m, __shfl_xor(m, 1));
            m = fmaxf(m, __shfl_xor(m, 2));
            m = fmaxf(m, __shfl_xor(m, 4));
            m = fmaxf(m, __shfl_xor(m, 8));
            tmax[mt][r] = m;
        }
    if (c == 0) {
#pragma unroll
        for (int mt = 0; mt < 3; mt++)
#pragma unroll
            for (int r = 0; r < 4; r++)
                red_m[w][mt * 16 + g * 4 + r] = tmax[mt][r];
    }
    __syncthreads();

    float tse[3][4];
#pragma unroll
    for (int mt = 0; mt < 3; mt++)
#pragma unroll
        for (int r = 0; r < 4; r++) {
            int row = mt * 16 + g * 4 + r;
            float m = fmaxf(fmaxf(red_m[0][row], red_m[1][row]),
                            fmaxf(red_m[2][row], red_m[3][row]));
            float s = 0.f;
#pragma unroll
            for (int nt = 0; nt < 4; nt++) {
                float p = __expf(scale * (acc[mt][nt][r] - m));
                acc[mt][nt][r] = p;
                s += p;
                p_lds[row * CHK + w * 64 + nt * 16 + c] = f2bf(p);
            }
            s += __shfl_xor(s, 1);
            s += __shfl_xor(s, 2);
            s += __shfl_xor(s, 4);
            s += __shfl_xor(s, 8);
            tse[mt][r] = s;
        }
    if (c == 0) {
#pragma unroll
        for (int mt = 0; mt < 3; mt++)
#pragma unroll
            for (int r = 0; r < 4; r++)
                red_se[w][mt * 16 + g * 4 + r] = tse[mt][r];
    }
    __syncthreads();

    if (tid < RPAD) {
        float mm = fmaxf(fmaxf(red_m[0][tid], red_m[1][tid]),
                         fmaxf(red_m[2][tid], red_m[3][tid]));
        float ss = red_se[0][tid] + red_se[1][tid] + red_se[2][tid] + red_se[3][tid];
        m_ws[blk * RPAD + tid]  = mm;
        se_ws[blk * RPAD + tid] = ss;
    }

    f32x4 acc2[3];
#pragma unroll
    for (int mt = 0; mt < 3; mt++) acc2[mt] = (f32x4){0.f, 0.f, 0.f, 0.f};

#pragma unroll
    for (int ks = 0; ks < 8; ks++) {
        int slot = ks * 4 + g;
        int d    = w * 16 + c;
        short8 bf = *reinterpret_cast<const short8*>(
            vt + d * CHK + ((slot ^ (d & 31)) << 3));
#pragma unroll
        for (int mt = 0; mt < 3; mt++) {
            short8 af = *reinterpret_cast<const short8*>(
                p_lds + (mt * 16 + c) * CHK + ks * 32 + g * 8);
            acc2[mt] = __builtin_amdgcn_mfma_f32_16x16x32_bf16(af, bf, acc2[mt], 0, 0, 0);
        }
    }

#pragma unroll
    for (int mt = 0; mt < 3; mt++)
#pragma unroll
        for (int r = 0; r < 4; r++) {
            int row = mt * 16 + g * 4 + r;
            pv_ws[((size_t)blk * RPAD + row) * 64 + w * 16 + c] = acc2[mt][r];
        }
}

// ---------------- K4: combine chunk partials, write selected rows ----------------
__global__ __launch_bounds__(256) void kernel_attn_comb(const int* __restrict__ top,
                                                        const float* __restrict__ m_ws,
                                                        const float* __restrict__ se_ws,
                                                        const float* __restrict__ pv_ws,
                                                        float* __restrict__ out) {
    int bh = blockIdx.x;
    int b = bh >> 3, h = bh & 7;
    const float scale = 0.125f;
    for (int idx = threadIdx.x; idx < UU * 64; idx += 256) {
        int r = idx >> 6, d = idx & 63;
        float mc[NCHK];
        float mm = -INFINITY;
#pragma unroll
        for (int ch = 0; ch < NCHK; ch++) {
            mc[ch] = m_ws[(bh * NCHK + ch) * RPAD + r];
            mm = fmaxf(mm, mc[ch]);
        }
        float num = 0.f, den = 0.f;
#pragma unroll
        for (int ch = 0; ch < NCHK; ch++) {
            float f = __expf(scale * (mc[ch] - mm));
            num += f * pv_ws[((size_t)(bh * NCHK + ch) * RPAD + r) * 64 + d];
            den += f * se_ws[(bh * NCHK + ch) * RPAD + r];
        }
        out[qkv_off(b, top[bh * UU + r], h, d)] = num / den;
    }
}

extern "C" void kernel_launch(void* const* d_in, const int* in_sizes, int n_in,
                              void* d_out, int out_size, void* d_ws, size_t ws_size,
                              hipStream_t stream) {
    const float* Q    = (const float*)d_in[0];
    const float* K    = (const float*)d_in[1];
    const float* V    = (const float*)d_in[2];
    const int*   sidx = (const int*)d_in[3];
    float* out = (float*)d_out;

    char* ws = (char*)d_ws;
    float* M     = (float*)(ws);                // 256 KiB
    int*   top   = (int*)  (ws + 262144);       // 9 KiB
    float* m_ws  = (float*)(ws + 272384);       // 48 KiB
    float* se_ws = (float*)(ws + 321536);       // 48 KiB
    float* pv_ws = (float*)(ws + 370688);       // 3 MiB

    kernel_M_cumsum <<<CSBLOCKS + MBLOCKS, 256, 0, stream>>>(Q, K, V, sidx, M, out);
    kernel_topk     <<<BH, 64, 0, stream>>>(M, top);
    kernel_attn_part<<<BH * NCHK, 256, 0, stream>>>(Q, K, V, top, m_ws, se_ws, pv_ws);
    kernel_attn_comb<<<BH, 256, 0, stream>>>(top, m_ws, se_ws, pv_ws, out);
}

// Round 16
// 71.247 us; speedup vs baseline: 1.1151x; 1.1151x over previous
//
#include <hip/hip_runtime.h>
#include <math.h>

#define BB 8
#define LL 1024
#define HH 8
#define DD 64
#define SS 35
#define UU 35
#define BH (BB*HH)
#define NCHK 4           // attention K/V chunks
#define CHK 256          // keys per chunk
#define RPAD 48          // padded row count (35 -> 48, 3 m-tiles)

#define CSBLOCKS BH      // 64 cumsum blocks (first in grid)
#define MBLOCKS (BB*LL)  // 8192 M blocks

typedef __attribute__((ext_vector_type(8))) short short8;
typedef __attribute__((ext_vector_type(4))) float f32x4;

__device__ __forceinline__ size_t qkv_off(int b, int l, int h, int d) {
    return (((size_t)b*LL + l)*HH + h)*DD + d;
}

__device__ __forceinline__ unsigned short f2bf(float x) {
    unsigned int u = __float_as_uint(x);
    u = (u + 0x7fffu + ((u >> 16) & 1u)) >> 16;
    return (unsigned short)u;
}

__device__ __forceinline__ short8 ld_bf8_g(const float* __restrict__ p) {
    float4 x = *reinterpret_cast<const float4*>(p);
    float4 y = *reinterpret_cast<const float4*>(p + 4);
    short8 r;
    r[0] = (short)f2bf(x.x); r[1] = (short)f2bf(x.y);
    r[2] = (short)f2bf(x.z); r[3] = (short)f2bf(x.w);
    r[4] = (short)f2bf(y.x); r[5] = (short)f2bf(y.y);
    r[6] = (short)f2bf(y.z); r[7] = (short)f2bf(y.w);
    return r;
}

// VALU-only 8-lane-group sum via DPP row_shr:N (dst[i]=src[i-N]); lane (lane&7)==7
// holds the group sum; chains stay within each 8-lane group. (Proven R10-R13.)
__device__ __forceinline__ float red8_shr(float p) {
    int t;
    t = __builtin_amdgcn_update_dpp(0, __float_as_int(p), 0x111, 0xF, 0xF, true); // row_shr:1
    p += __int_as_float(t);
    t = __builtin_amdgcn_update_dpp(0, __float_as_int(p), 0x112, 0xF, 0xF, true); // row_shr:2
    p += __int_as_float(t);
    t = __builtin_amdgcn_update_dpp(0, __float_as_int(p), 0x114, 0xF, 0xF, true); // row_shr:4
    p += __int_as_float(t);
    return p;
}

// wave-wide fmax: 4 DPP stages (intra-row) + 2 shfl (cross-row). (Proven R14.)
__device__ __forceinline__ float wave_fmax64(float x) {
    int t;
    t = __builtin_amdgcn_update_dpp(0, __float_as_int(x), 0xB1, 0xF, 0xF, true);
    x = fmaxf(x, __int_as_float(t));
    t = __builtin_amdgcn_update_dpp(0, __float_as_int(x), 0x4E, 0xF, 0xF, true);
    x = fmaxf(x, __int_as_float(t));
    t = __builtin_amdgcn_update_dpp(0, __float_as_int(x), 0x141, 0xF, 0xF, true);
    x = fmaxf(x, __int_as_float(t));
    t = __builtin_amdgcn_update_dpp(0, __float_as_int(x), 0x140, 0xF, 0xF, true);
    x = fmaxf(x, __int_as_float(t));
    x = fmaxf(x, __shfl_xor(x, 16));
    x = fmaxf(x, __shfl_xor(x, 32));
    return x;
}

__device__ __forceinline__ int wave_imin64(int x) {
    int t;
    t = __builtin_amdgcn_update_dpp(0, x, 0xB1, 0xF, 0xF, true);  x = (t < x) ? t : x;
    t = __builtin_amdgcn_update_dpp(0, x, 0x4E, 0xF, 0xF, true);  x = (t < x) ? t : x;
    t = __builtin_amdgcn_update_dpp(0, x, 0x141, 0xF, 0xF, true); x = (t < x) ? t : x;
    t = __builtin_amdgcn_update_dpp(0, x, 0x140, 0xF, 0xF, true); x = (t < x) ? t : x;
    int y;
    y = __shfl_xor(x, 16); x = (y < x) ? y : x;
    y = __shfl_xor(x, 32); x = (y < x) ? y : x;
    return x;
}

// ---------------- K1: cumsum (blocks 0..63) + M-gather, VGPR path (R13, measured 40-46us) ----------------
__global__ __launch_bounds__(512, 2) void kernel_M_cumsum(const float* __restrict__ Q,
                                                          const float* __restrict__ K,
                                                          const float* __restrict__ V,
                                                          const int*   __restrict__ sidx,
                                                          float* __restrict__ M,
                                                          float* __restrict__ out) {
    int blk = blockIdx.x;
    if (blk < CSBLOCKS) {
        // ---- full cumsum for one (b,h): 8 segs x 128 rows, two-pass scan ----
        __shared__ float partial[8][64];
        int bh = blk;
        int b = bh >> 3, h = bh & 7;
        int d = threadIdx.x & 63, seg = threadIdx.x >> 6;
        int l0 = seg * 128;
        const float* vp = V + qkv_off(b, l0, h, d);

        float s = 0.f;
#pragma unroll 8
        for (int i = 0; i < 128; i++) s += vp[(size_t)i * (HH * DD)];
        partial[seg][d] = s;
        __syncthreads();
        float run = 0.f;
#pragma unroll
        for (int ss = 0; ss < 7; ss++) {
            float v = partial[ss][d];
            run += (ss < seg) ? v : 0.f;
        }
        float* op = out + qkv_off(b, l0, h, d);
#pragma unroll 8
        for (int i = 0; i < 128; i++) {
            run += vp[(size_t)i * (HH * DD)];
            op[(size_t)i * (HH * DD)] = run / (float)(l0 + i + 1);
        }
    } else {
        // ---- M: one block per (b,q); wave w owns samples {w, w+8, ...} ----
        __shared__ float s_mx[8][8];
        __shared__ float s_sm[8][8];
        int mblk = blk - CSBLOCKS;       // CSBLOCKS%8==0 keeps XCD pinning
        int b = mblk & 7;                // pins this b's K-slice to one XCD's L2
        int q = mblk >> 3;
        int tid = threadIdx.x;
        int w = tid >> 6, lane = tid & 63;
        int h = lane >> 3, j = lane & 7, dsub = j * 4;

        const float* qb = Q + ((size_t)(b * LL + q) * HH + h) * DD + dsub;
        f32x4 q0 = *reinterpret_cast<const f32x4*>(qb);
        f32x4 q1 = *reinterpret_cast<const f32x4*>(qb + 32);

        const int* sq = sidx + q * SS;
        int sl[5];
#pragma unroll
        for (int i = 0; i < 5; i++) {
            int s = w + 8 * i;
            sl[i] = sq[s < SS ? s : 0];   // wave-uniform
        }

        const float* kbase = K + (size_t)b * (LL * HH * DD) + h * DD + dsub;
        f32x4 ka[5], kc[5];
#pragma unroll
        for (int i = 0; i < 5; i++) {
            const float* kp = kbase + (size_t)sl[i] * (HH * DD);
            ka[i] = *reinterpret_cast<const f32x4*>(kp);
            kc[i] = *reinterpret_cast<const f32x4*>(kp + 32);
        }

        float mx = -INFINITY, sm = 0.f;
#pragma unroll
        for (int i = 0; i < 5; i++) {
            float d = q0.x * ka[i].x + q0.y * ka[i].y + q0.z * ka[i].z + q0.w * ka[i].w
                    + q1.x * kc[i].x + q1.y * kc[i].y + q1.z * kc[i].z + q1.w * kc[i].w;
            d = red8_shr(d);              // lane j==7 holds the full 64-d dot
            bool valid = (i < 4) || (w < 3);
            if (valid) { mx = fmaxf(mx, d); sm += d; }
        }
        if (j == 7) { s_mx[w][h] = mx; s_sm[w][h] = sm; }
        __syncthreads();
        if (tid < 8) {
            float m2 = -INFINITY, s2 = 0.f;
#pragma unroll
            for (int ww = 0; ww < 8; ww++) {
                m2 = fmaxf(m2, s_mx[ww][tid]);
                s2 += s_sm[ww][tid];
            }
            M[(b * HH + tid) * LL + q] = m2 - s2 * (1.0f / LL);
        }
    }
}

// ---------------- K2: topk, DPP-accelerated single-wave argmax (R14) ----------------
__global__ __launch_bounds__(64, 4) void kernel_topk(const float* __restrict__ M,
                                                     int* __restrict__ top) {
    int bh = blockIdx.x, lane = threadIdx.x;
    float v[16];
#pragma unroll
    for (int i = 0; i < 16; i++) v[i] = M[bh * LL + i * 64 + lane];

    for (int k = 0; k < UU; k++) {
        float bv = -INFINITY; int bslot = 0;
#pragma unroll
        for (int i = 0; i < 16; i++) {
            if (v[i] > bv) { bv = v[i]; bslot = i; }      // ascending i -> lowest idx on tie
        }
        float wm = wave_fmax64(bv);
        int gidx = (bv == wm) ? (bslot * 64 + lane) : 0x7fffffff;
        int widx = wave_imin64(gidx);                      // min global index among ties
        if (lane == 0) top[bh * UU + k] = widx;
        if ((widx & 63) == lane) {
            int slot = widx >> 6;
#pragma unroll
            for (int i = 0; i < 16; i++) if (i == slot) v[i] = -INFINITY;
        }
    }
}

// ---------------- K3: MFMA flash-attention partials per (bh, chunk) ----------------
__global__ __launch_bounds__(256) void kernel_attn_part(const float* __restrict__ Q,
                                                        const float* __restrict__ K,
                                                        const float* __restrict__ V,
                                                        const int*   __restrict__ top,
                                                        float* __restrict__ m_ws,
                                                        float* __restrict__ se_ws,
                                                        float* __restrict__ pv_ws) {
    __shared__ unsigned short vt[64 * CHK];      // V^T, 16B-slot swizzled
    __shared__ unsigned short p_lds[RPAD * CHK]; // P (exp'd scores), bf16
    __shared__ float red_m[4][RPAD];
    __shared__ float red_se[4][RPAD];
    __shared__ int   qpos_s[RPAD];

    const int blk = blockIdx.x;          // bh*NCHK + ch
    const int bh  = blk >> 2;
    const int ch  = blk & 3;
    const int b   = bh >> 3, h = bh & 7;
    const int l0  = ch * CHK;
    const int tid = threadIdx.x;
    const int w    = tid >> 6;
    const int lane = tid & 63;
    const int c    = lane & 15;
    const int g    = lane >> 4;
    const float scale = 0.125f;

    if (tid < RPAD) qpos_s[tid] = top[bh * UU + (tid < UU ? tid : UU - 1)];

#pragma unroll
    for (int i = 0; i < 8; i++) {
        int task = i * 256 + tid;
        int d   = task & 63;
        int lq8 = task >> 6;
        float vv[8];
#pragma unroll
        for (int jj = 0; jj < 8; jj++)
            vv[jj] = V[qkv_off(b, l0 + lq8 * 8 + jj, h, d)];
        short8 pk;
#pragma unroll
        for (int jj = 0; jj < 8; jj++) pk[jj] = (short)f2bf(vv[jj]);
        *reinterpret_cast<short8*>(vt + d * CHK + (((lq8 ^ (d & 31)) << 3))) = pk;
    }
    __syncthreads();

    f32x4 acc[3][4];
#pragma unroll
    for (int mt = 0; mt < 3; mt++)
#pragma unroll
        for (int nt = 0; nt < 4; nt++) acc[mt][nt] = (f32x4){0.f, 0.f, 0.f, 0.f};

#pragma unroll
    for (int ks = 0; ks < 2; ks++) {
        int k0 = ks * 32 + g * 8;
        short8 af[3];
#pragma unroll
        for (int mt = 0; mt < 3; mt++) {
            int row = mt * 16 + c;
            af[mt] = ld_bf8_g(Q + qkv_off(b, qpos_s[row], h, k0));
        }
#pragma unroll
        for (int nt = 0; nt < 4; nt++) {
            int kl = l0 + w * 64 + nt * 16 + c;
            short8 bf = ld_bf8_g(K + qkv_off(b, kl, h, k0));
#pragma unroll
            for (int mt = 0; mt < 3; mt++)
                acc[mt][nt] = __builtin_amdgcn_mfma_f32_16x16x32_bf16(af[mt], bf, acc[mt][nt], 0, 0, 0);
        }
    }

    float tmax[3][4];
#pragma unroll
    for (int mt = 0; mt < 3; mt++)
#pragma unroll
        for (int r = 0; r < 4; r++) {
            float m = fmaxf(fmaxf(acc[mt][0][r], acc[mt][1][r]),
                            fmaxf(acc[mt][2][r], acc[mt][3][r]));
            m = fmaxf(m, __shfl_xor(m, 1));
            m = fmaxf(m, __shfl_xor(m, 2));
            m = fmaxf(m, __shfl_xor(m, 4));
            m = fmaxf(m, __shfl_xor(m, 8));
            tmax[mt][r] = m;
        }
    if (c == 0) {
#pragma unroll
        for (int mt = 0; mt < 3; mt++)
#pragma unroll
            for (int r = 0; r < 4; r++)
                red_m[w][mt * 16 + g * 4 + r] = tmax[mt][r];
    }
    __syncthreads();

    float tse[3][4];
#pragma unroll
    for (int mt = 0; mt < 3; mt++)
#pragma unroll
        for (int r = 0; r < 4; r++) {
            int row = mt * 16 + g * 4 + r;
            float m = fmaxf(fmaxf(red_m[0][row], red_m[1][row]),
                            fmaxf(red_m[2][row], red_m[3][row]));
            float s = 0.f;
#pragma unroll
            for (int nt = 0; nt < 4; nt++) {
                float p = __expf(scale * (acc[mt][nt][r] - m));
                acc[mt][nt][r] = p;
                s += p;
                p_lds[row * CHK + w * 64 + nt * 16 + c] = f2bf(p);
            }
            s += __shfl_xor(s, 1);
            s += __shfl_xor(s, 2);
            s += __shfl_xor(s, 4);
            s += __shfl_xor(s, 8);
            tse[mt][r] = s;
        }
    if (c == 0) {
#pragma unroll
        for (int mt = 0; mt < 3; mt++)
#pragma unroll
            for (int r = 0; r < 4; r++)
                red_se[w][mt * 16 + g * 4 + r] = tse[mt][r];
    }
    __syncthreads();

    if (tid < RPAD) {
        float mm = fmaxf(fmaxf(red_m[0][tid], red_m[1][tid]),
                         fmaxf(red_m[2][tid], red_m[3][tid]));
        float ss = red_se[0][tid] + red_se[1][tid] + red_se[2][tid] + red_se[3][tid];
        m_ws[blk * RPAD + tid]  = mm;
        se_ws[blk * RPAD + tid] = ss;
    }

    f32x4 acc2[3];
#pragma unroll
    for (int mt = 0; mt < 3; mt++) acc2[mt] = (f32x4){0.f, 0.f, 0.f, 0.f};

#pragma unroll
    for (int ks = 0; ks < 8; ks++) {
        int slot = ks * 4 + g;
        int d    = w * 16 + c;
        short8 bf = *reinterpret_cast<const short8*>(
            vt + d * CHK + ((slot ^ (d & 31)) << 3));
#pragma unroll
        for (int mt = 0; mt < 3; mt++) {
            short8 af = *reinterpret_cast<const short8*>(
                p_lds + (mt * 16 + c) * CHK + ks * 32 + g * 8);
            acc2[mt] = __builtin_amdgcn_mfma_f32_16x16x32_bf16(af, bf, acc2[mt], 0, 0, 0);
        }
    }

#pragma unroll
    for (int mt = 0; mt < 3; mt++)
#pragma unroll
        for (int r = 0; r < 4; r++) {
            int row = mt * 16 + g * 4 + r;
            pv_ws[((size_t)blk * RPAD + row) * 64 + w * 16 + c] = acc2[mt][r];
        }
}

// ---------------- K4: combine chunk partials, write selected rows ----------------
__global__ __launch_bounds__(256) void kernel_attn_comb(const int* __restrict__ top,
                                                        const float* __restrict__ m_ws,
                                                        const float* __restrict__ se_ws,
                                                        const float* __restrict__ pv_ws,
                                                        float* __restrict__ out) {
    int bh = blockIdx.x;
    int b = bh >> 3, h = bh & 7;
    const float scale = 0.125f;
    for (int idx = threadIdx.x; idx < UU * 64; idx += 256) {
        int r = idx >> 6, d = idx & 63;
        float mc[NCHK];
        float mm = -INFINITY;
#pragma unroll
        for (int ch = 0; ch < NCHK; ch++) {
            mc[ch] = m_ws[(bh * NCHK + ch) * RPAD + r];
            mm = fmaxf(mm, mc[ch]);
        }
        float num = 0.f, den = 0.f;
#pragma unroll
        for (int ch = 0; ch < NCHK; ch++) {
            float f = __expf(scale * (mc[ch] - mm));
            num += f * pv_ws[((size_t)(bh * NCHK + ch) * RPAD + r) * 64 + d];
            den += f * se_ws[(bh * NCHK + ch) * RPAD + r];
        }
        out[qkv_off(b, top[bh * UU + r], h, d)] = num / den;
    }
}

extern "C" void kernel_launch(void* const* d_in, const int* in_sizes, int n_in,
                              void* d_out, int out_size, void* d_ws, size_t ws_size,
                              hipStream_t stream) {
    const float* Q    = (const float*)d_in[0];
    const float* K    = (const float*)d_in[1];
    const float* V    = (const float*)d_in[2];
    const int*   sidx = (const int*)d_in[3];
    float* out = (float*)d_out;

    char* ws = (char*)d_ws;
    float* M     = (float*)(ws);                // 256 KiB
    int*   top   = (int*)  (ws + 262144);       // 9 KiB
    float* m_ws  = (float*)(ws + 272384);       // 48 KiB
    float* se_ws = (float*)(ws + 321536);       // 48 KiB
    float* pv_ws = (float*)(ws + 370688);       // 3 MiB

    kernel_M_cumsum <<<CSBLOCKS + MBLOCKS, 512, 0, stream>>>(Q, K, V, sidx, M, out);
    kernel_topk     <<<BH, 64, 0, stream>>>(M, top);
    kernel_attn_part<<<BH * NCHK, 256, 0, stream>>>(Q, K, V, top, m_ws, se_ws, pv_ws);
    kernel_attn_comb<<<BH, 256, 0, stream>>>(top, m_ws, se_ws, pv_ws, out);
}

// Round 17
// 68.217 us; speedup vs baseline: 1.1646x; 1.0444x over previous
//
#include <hip/hip_runtime.h>
#include <math.h>

#define BB 8
#define LL 1024
#define HH 8
#define DD 64
#define SS 35
#define UU 35
#define BH (BB*HH)
#define NCHK 4           // attention K/V chunks
#define CHK 256          // keys per chunk
#define RPAD 48          // padded row count (35 -> 48, 3 m-tiles)

#define CSBLOCKS BH      // 64 cumsum blocks (first in grid)
#define MBLOCKS (BB*LL)  // 8192 M blocks

typedef __attribute__((ext_vector_type(8))) short short8;
typedef __attribute__((ext_vector_type(4))) float f32x4;

__device__ __forceinline__ size_t qkv_off(int b, int l, int h, int d) {
    return (((size_t)b*LL + l)*HH + h)*DD + d;
}

__device__ __forceinline__ unsigned short f2bf(float x) {
    unsigned int u = __float_as_uint(x);
    u = (u + 0x7fffu + ((u >> 16) & 1u)) >> 16;
    return (unsigned short)u;
}

__device__ __forceinline__ short8 ld_bf8_g(const float* __restrict__ p) {
    float4 x = *reinterpret_cast<const float4*>(p);
    float4 y = *reinterpret_cast<const float4*>(p + 4);
    short8 r;
    r[0] = (short)f2bf(x.x); r[1] = (short)f2bf(x.y);
    r[2] = (short)f2bf(x.z); r[3] = (short)f2bf(x.w);
    r[4] = (short)f2bf(y.x); r[5] = (short)f2bf(y.y);
    r[6] = (short)f2bf(y.z); r[7] = (short)f2bf(y.w);
    return r;
}

// VALU-only 8-lane-group sum via DPP row_shr:N (dst[i]=src[i-N]); lane (lane&7)==7
// holds the group sum; chains stay within each 8-lane group. (Proven R10-R16.)
__device__ __forceinline__ float red8_shr(float p) {
    int t;
    t = __builtin_amdgcn_update_dpp(0, __float_as_int(p), 0x111, 0xF, 0xF, true); // row_shr:1
    p += __int_as_float(t);
    t = __builtin_amdgcn_update_dpp(0, __float_as_int(p), 0x112, 0xF, 0xF, true); // row_shr:2
    p += __int_as_float(t);
    t = __builtin_amdgcn_update_dpp(0, __float_as_int(p), 0x114, 0xF, 0xF, true); // row_shr:4
    p += __int_as_float(t);
    return p;
}

// wave-wide fmax / imin: butterfly DPP (all lanes receive the result). (Proven R14-R16.)
__device__ __forceinline__ float wave_fmax64(float x) {
    int t;
    t = __builtin_amdgcn_update_dpp(0, __float_as_int(x), 0xB1, 0xF, 0xF, true);
    x = fmaxf(x, __int_as_float(t));
    t = __builtin_amdgcn_update_dpp(0, __float_as_int(x), 0x4E, 0xF, 0xF, true);
    x = fmaxf(x, __int_as_float(t));
    t = __builtin_amdgcn_update_dpp(0, __float_as_int(x), 0x141, 0xF, 0xF, true);
    x = fmaxf(x, __int_as_float(t));
    t = __builtin_amdgcn_update_dpp(0, __float_as_int(x), 0x140, 0xF, 0xF, true);
    x = fmaxf(x, __int_as_float(t));
    x = fmaxf(x, __shfl_xor(x, 16));
    x = fmaxf(x, __shfl_xor(x, 32));
    return x;
}

__device__ __forceinline__ int wave_imin64(int x) {
    int t;
    t = __builtin_amdgcn_update_dpp(0, x, 0xB1, 0xF, 0xF, true);  x = (t < x) ? t : x;
    t = __builtin_amdgcn_update_dpp(0, x, 0x4E, 0xF, 0xF, true);  x = (t < x) ? t : x;
    t = __builtin_amdgcn_update_dpp(0, x, 0x141, 0xF, 0xF, true); x = (t < x) ? t : x;
    t = __builtin_amdgcn_update_dpp(0, x, 0x140, 0xF, 0xF, true); x = (t < x) ? t : x;
    int y;
    y = __shfl_xor(x, 16); x = (y < x) ? y : x;
    y = __shfl_xor(x, 32); x = (y < x) ? y : x;
    return x;
}

// ---------------- K1: cumsum (blocks 0..63) + M-gather, VGPR path (R16, 45.5us) ----------------
__global__ __launch_bounds__(512, 2) void kernel_M_cumsum(const float* __restrict__ Q,
                                                          const float* __restrict__ K,
                                                          const float* __restrict__ V,
                                                          const int*   __restrict__ sidx,
                                                          float* __restrict__ M,
                                                          float* __restrict__ out) {
    int blk = blockIdx.x;
    if (blk < CSBLOCKS) {
        // ---- full cumsum for one (b,h): 8 segs x 128 rows, two-pass scan ----
        __shared__ float partial[8][64];
        int bh = blk;
        int b = bh >> 3, h = bh & 7;
        int d = threadIdx.x & 63, seg = threadIdx.x >> 6;
        int l0 = seg * 128;
        const float* vp = V + qkv_off(b, l0, h, d);

        float s = 0.f;
#pragma unroll 8
        for (int i = 0; i < 128; i++) s += vp[(size_t)i * (HH * DD)];
        partial[seg][d] = s;
        __syncthreads();
        float run = 0.f;
#pragma unroll
        for (int ss = 0; ss < 7; ss++) {
            float v = partial[ss][d];
            run += (ss < seg) ? v : 0.f;
        }
        float* op = out + qkv_off(b, l0, h, d);
#pragma unroll 8
        for (int i = 0; i < 128; i++) {
            run += vp[(size_t)i * (HH * DD)];
            op[(size_t)i * (HH * DD)] = run / (float)(l0 + i + 1);
        }
    } else {
        // ---- M: one block per (b,q); wave w owns samples {w, w+8, ...} ----
        __shared__ float s_mx[8][8];
        __shared__ float s_sm[8][8];
        int mblk = blk - CSBLOCKS;       // CSBLOCKS%8==0 keeps XCD pinning
        int b = mblk & 7;                // pins this b's K-slice to one XCD's L2
        int q = mblk >> 3;
        int tid = threadIdx.x;
        int w = tid >> 6, lane = tid & 63;
        int h = lane >> 3, j = lane & 7, dsub = j * 4;

        const float* qb = Q + ((size_t)(b * LL + q) * HH + h) * DD + dsub;
        f32x4 q0 = *reinterpret_cast<const f32x4*>(qb);
        f32x4 q1 = *reinterpret_cast<const f32x4*>(qb + 32);

        const int* sq = sidx + q * SS;
        int sl[5];
#pragma unroll
        for (int i = 0; i < 5; i++) {
            int s = w + 8 * i;
            sl[i] = sq[s < SS ? s : 0];   // wave-uniform
        }

        const float* kbase = K + (size_t)b * (LL * HH * DD) + h * DD + dsub;
        f32x4 ka[5], kc[5];
#pragma unroll
        for (int i = 0; i < 5; i++) {
            const float* kp = kbase + (size_t)sl[i] * (HH * DD);
            ka[i] = *reinterpret_cast<const f32x4*>(kp);
            kc[i] = *reinterpret_cast<const f32x4*>(kp + 32);
        }

        float mx = -INFINITY, sm = 0.f;
#pragma unroll
        for (int i = 0; i < 5; i++) {
            float d = q0.x * ka[i].x + q0.y * ka[i].y + q0.z * ka[i].z + q0.w * ka[i].w
                    + q1.x * kc[i].x + q1.y * kc[i].y + q1.z * kc[i].z + q1.w * kc[i].w;
            d = red8_shr(d);              // lane j==7 holds the full 64-d dot
            bool valid = (i < 4) || (w < 3);
            if (valid) { mx = fmaxf(mx, d); sm += d; }
        }
        if (j == 7) { s_mx[w][h] = mx; s_sm[w][h] = sm; }
        __syncthreads();
        if (tid < 8) {
            float m2 = -INFINITY, s2 = 0.f;
#pragma unroll
            for (int ww = 0; ww < 8; ww++) {
                m2 = fmaxf(m2, s_mx[ww][tid]);
                s2 += s_sm[ww][tid];
            }
            M[(b * HH + tid) * LL + q] = m2 - s2 * (1.0f / LL);
        }
    }
}

// ---------------- K2: attn_part with FUSED topk (wave 0) ∥ V-staging (waves 1-3) ----------------
__global__ __launch_bounds__(256) void kernel_attn_part(const float* __restrict__ Q,
                                                        const float* __restrict__ K,
                                                        const float* __restrict__ V,
                                                        const float* __restrict__ M,
                                                        int*   __restrict__ top,
                                                        float* __restrict__ m_ws,
                                                        float* __restrict__ se_ws,
                                                        float* __restrict__ pv_ws) {
    __shared__ unsigned short vt[64 * CHK];      // V^T, 16B-slot swizzled
    __shared__ unsigned short p_lds[RPAD * CHK]; // P (exp'd scores), bf16
    __shared__ float red_m[4][RPAD];
    __shared__ float red_se[4][RPAD];
    __shared__ int   qpos_s[RPAD];

    const int blk = blockIdx.x;          // bh*NCHK + ch
    const int bh  = blk >> 2;
    const int ch  = blk & 3;
    const int b   = bh >> 3, h = bh & 7;
    const int l0  = ch * CHK;
    const int tid = threadIdx.x;
    const int w    = tid >> 6;
    const int lane = tid & 63;
    const int c    = lane & 15;
    const int g    = lane >> 4;
    const float scale = 0.125f;

    if (w == 0) {
        // ---- wave 0: top-35 from M (R14 DPP argmax), redundant across the bh's 4 blocks ----
        float v[16];
#pragma unroll
        for (int i = 0; i < 16; i++) v[i] = M[bh * LL + i * 64 + lane];
        int last = 0;
        for (int k = 0; k < UU; k++) {
            float bv = -INFINITY; int bslot = 0;
#pragma unroll
            for (int i = 0; i < 16; i++) {
                if (v[i] > bv) { bv = v[i]; bslot = i; }  // ascending i -> lowest idx on tie
            }
            float wm = wave_fmax64(bv);
            int gidx = (bv == wm) ? (bslot * 64 + lane) : 0x7fffffff;
            int widx = wave_imin64(gidx);                  // all lanes hold result
            if (lane == 0) qpos_s[k] = widx;
            if (k == UU - 1) last = widx;
            if ((widx & 63) == lane) {
                int slot = widx >> 6;
#pragma unroll
                for (int i = 0; i < 16; i++) if (i == slot) v[i] = -INFINITY;
            }
        }
        if (lane >= UU && lane < RPAD) qpos_s[lane] = last;
        if (ch == 0 && lane < UU) top[bh * UU + lane] = qpos_s[lane];  // persist for comb
    } else {
        // ---- waves 1-3: stage V^T chunk (2048 tasks over 192 threads) ----
        int t3 = tid - 64;
#pragma unroll
        for (int i = 0; i < 11; i++) {
            int task = i * 192 + t3;
            if (task < 2048) {
                int d   = task & 63;
                int lq8 = task >> 6;
                float vv[8];
#pragma unroll
                for (int jj = 0; jj < 8; jj++)
                    vv[jj] = V[qkv_off(b, l0 + lq8 * 8 + jj, h, d)];
                short8 pk;
#pragma unroll
                for (int jj = 0; jj < 8; jj++) pk[jj] = (short)f2bf(vv[jj]);
                *reinterpret_cast<short8*>(vt + d * CHK + (((lq8 ^ (d & 31)) << 3))) = pk;
            }
        }
    }
    __syncthreads();

    f32x4 acc[3][4];
#pragma unroll
    for (int mt = 0; mt < 3; mt++)
#pragma unroll
        for (int nt = 0; nt < 4; nt++) acc[mt][nt] = (f32x4){0.f, 0.f, 0.f, 0.f};

#pragma unroll
    for (int ks = 0; ks < 2; ks++) {
        int k0 = ks * 32 + g * 8;
        short8 af[3];
#pragma unroll
        for (int mt = 0; mt < 3; mt++) {
            int row = mt * 16 + c;
            af[mt] = ld_bf8_g(Q + qkv_off(b, qpos_s[row], h, k0));
        }
#pragma unroll
        for (int nt = 0; nt < 4; nt++) {
            int kl = l0 + w * 64 + nt * 16 + c;
            short8 bf = ld_bf8_g(K + qkv_off(b, kl, h, k0));
#pragma unroll
            for (int mt = 0; mt < 3; mt++)
                acc[mt][nt] = __builtin_amdgcn_mfma_f32_16x16x32_bf16(af[mt], bf, acc[mt][nt], 0, 0, 0);
        }
    }

    float tmax[3][4];
#pragma unroll
    for (int mt = 0; mt < 3; mt++)
#pragma unroll
        for (int r = 0; r < 4; r++) {
            float m = fmaxf(fmaxf(acc[mt][0][r], acc[mt][1][r]),
                            fmaxf(acc[mt][2][r], acc[mt][3][r]));
            m = fmaxf(m, __shfl_xor(m, 1));
            m = fmaxf(m, __shfl_xor(m, 2));
            m = fmaxf(m, __shfl_xor(m, 4));
            m = fmaxf(m, __shfl_xor(m, 8));
            tmax[mt][r] = m;
        }
    if (c == 0) {
#pragma unroll
        for (int mt = 0; mt < 3; mt++)
#pragma unroll
            for (int r = 0; r < 4; r++)
                red_m[w][mt * 16 + g * 4 + r] = tmax[mt][r];
    }
    __syncthreads();

    float tse[3][4];
#pragma unroll
    for (int mt = 0; mt < 3; mt++)
#pragma unroll
        for (int r = 0; r < 4; r++) {
            int row = mt * 16 + g * 4 + r;
            float m = fmaxf(fmaxf(red_m[0][row], red_m[1][row]),
                            fmaxf(red_m[2][row], red_m[3][row]));
            float s = 0.f;
#pragma unroll
            for (int nt = 0; nt < 4; nt++) {
                float p = __expf(scale * (acc[mt][nt][r] - m));
                acc[mt][nt][r] = p;
                s += p;
                p_lds[row * CHK + w * 64 + nt * 16 + c] = f2bf(p);
            }
            s += __shfl_xor(s, 1);
            s += __shfl_xor(s, 2);
            s += __shfl_xor(s, 4);
            s += __shfl_xor(s, 8);
            tse[mt][r] = s;
        }
    if (c == 0) {
#pragma unroll
        for (int mt = 0; mt < 3; mt++)
#pragma unroll
            for (int r = 0; r < 4; r++)
                red_se[w][mt * 16 + g * 4 + r] = tse[mt][r];
    }
    __syncthreads();

    if (tid < RPAD) {
        float mm = fmaxf(fmaxf(red_m[0][tid], red_m[1][tid]),
                         fmaxf(red_m[2][tid], red_m[3][tid]));
        float ss = red_se[0][tid] + red_se[1][tid] + red_se[2][tid] + red_se[3][tid];
        m_ws[blk * RPAD + tid]  = mm;
        se_ws[blk * RPAD + tid] = ss;
    }

    f32x4 acc2[3];
#pragma unroll
    for (int mt = 0; mt < 3; mt++) acc2[mt] = (f32x4){0.f, 0.f, 0.f, 0.f};

#pragma unroll
    for (int ks = 0; ks < 8; ks++) {
        int slot = ks * 4 + g;
        int d    = w * 16 + c;
        short8 bf = *reinterpret_cast<const short8*>(
            vt + d * CHK + ((slot ^ (d & 31)) << 3));
#pragma unroll
        for (int mt = 0; mt < 3; mt++) {
            short8 af = *reinterpret_cast<const short8*>(
                p_lds + (mt * 16 + c) * CHK + ks * 32 + g * 8);
            acc2[mt] = __builtin_amdgcn_mfma_f32_16x16x32_bf16(af, bf, acc2[mt], 0, 0, 0);
        }
    }

#pragma unroll
    for (int mt = 0; mt < 3; mt++)
#pragma unroll
        for (int r = 0; r < 4; r++) {
            int row = mt * 16 + g * 4 + r;
            pv_ws[((size_t)blk * RPAD + row) * 64 + w * 16 + c] = acc2[mt][r];
        }
}

// ---------------- K3: combine chunk partials, write selected rows ----------------
__global__ __launch_bounds__(256) void kernel_attn_comb(const int* __restrict__ top,
                                                        const float* __restrict__ m_ws,
                                                        const float* __restrict__ se_ws,
                                                        const float* __restrict__ pv_ws,
                                                        float* __restrict__ out) {
    int bh = blockIdx.x;
    int b = bh >> 3, h = bh & 7;
    const float scale = 0.125f;
    for (int idx = threadIdx.x; idx < UU * 64; idx += 256) {
        int r = idx >> 6, d = idx & 63;
        float mc[NCHK];
        float mm = -INFINITY;
#pragma unroll
        for (int ch = 0; ch < NCHK; ch++) {
            mc[ch] = m_ws[(bh * NCHK + ch) * RPAD + r];
            mm = fmaxf(mm, mc[ch]);
        }
        float num = 0.f, den = 0.f;
#pragma unroll
        for (int ch = 0; ch < NCHK; ch++) {
            float f = __expf(scale * (mc[ch] - mm));
            num += f * pv_ws[((size_t)(bh * NCHK + ch) * RPAD + r) * 64 + d];
            den += f * se_ws[(bh * NCHK + ch) * RPAD + r];
        }
        out[qkv_off(b, top[bh * UU + r], h, d)] = num / den;
    }
}

extern "C" void kernel_launch(void* const* d_in, const int* in_sizes, int n_in,
                              void* d_out, int out_size, void* d_ws, size_t ws_size,
                              hipStream_t stream) {
    const float* Q    = (const float*)d_in[0];
    const float* K    = (const float*)d_in[1];
    const float* V    = (const float*)d_in[2];
    const int*   sidx = (const int*)d_in[3];
    float* out = (float*)d_out;

    char* ws = (char*)d_ws;
    float* M     = (float*)(ws);                // 256 KiB
    int*   top   = (int*)  (ws + 262144);       // 9 KiB
    float* m_ws  = (float*)(ws + 272384);       // 48 KiB
    float* se_ws = (float*)(ws + 321536);       // 48 KiB
    float* pv_ws = (float*)(ws + 370688);       // 3 MiB

    kernel_M_cumsum <<<CSBLOCKS + MBLOCKS, 512, 0, stream>>>(Q, K, V, sidx, M, out);
    kernel_attn_part<<<BH * NCHK, 256, 0, stream>>>(Q, K, V, M, top, m_ws, se_ws, pv_ws);
    kernel_attn_comb<<<BH, 256, 0, stream>>>(top, m_ws, se_ws, pv_ws, out);
}